// Round 5
// baseline (342.336 us; speedup 1.0000x reference)
//
#include <hip/hip_runtime.h>

typedef _Float16 f16x4 __attribute__((ext_vector_type(4)));
typedef _Float16 f16x8 __attribute__((ext_vector_type(8)));
typedef float    f32x16 __attribute__((ext_vector_type(16)));
typedef float    f32x4v __attribute__((ext_vector_type(4)));

// ---- ws byte offsets (total 8,486,912 B) ----
#define HN_OFF   0u                      // 8192 fp32: 0.5*||e||^2   (32 KB)
#define BEST_OFF 32768u                  // 8192 u64 packed best     (64 KB)
#define ERH_OFF  98304u                  // e-hi, TILED+SWIZZLED     (2 MB)
#define ERL_OFF  (98304u + 2097152u)     // e-lo * 2^11, same layout
#define XRH_OFF  (98304u + 2u * 2097152u) // x-hi, row-major
#define XRL_OFF  (98304u + 3u * 2097152u) // x-lo * 2^11, row-major

// ---- out layout (float indices): [quantized NCHW 1M][encodings 64M] ----
#define OUT_Q    0
#define OUT_ENC  1048576

// e-plane DRAM layout = k2's LDS image: 128 tiles of 64 codes; within a tile,
// f16 elem (w, c) stored at tile*8192 + w*128 + ((c>>3) ^ (w&15))*8 + (c&7).
// Bakes the bank-conflict XOR swizzle into DRAM so global_load_lds can stage
// with a LINEAR wave-uniform destination (rule #21 / m173).

__device__ __forceinline__ void gll16(const void* g, void* l) {
    __builtin_amdgcn_global_load_lds(
        (const __attribute__((address_space(1))) unsigned int*)g,
        (__attribute__((address_space(3))) unsigned int*)l, 16, 0, 0);
}

// K1: split x,e into f16 hi + scaled-lo planes; e-planes written pre-swizzled
// tile-image; fused 0.5*||e||^2; zero-init packed-best array.
__global__ __launch_bounds__(256) void k1_convert(const float* __restrict__ x,
                                                  const float* __restrict__ e,
                                                  char* __restrict__ wsb) {
    int bx = blockIdx.x, tid = threadIdx.x;
    bool is_e = bx < 1024;
    const float* src = is_e ? e : x;
    int sec = is_e ? bx : bx - 1024;
    size_t off = (size_t)sec * 1024 + tid * 4;      // float-element offset
    float4 v = *(const float4*)(src + off);

    f16x4 hi, lo;
    hi[0] = (_Float16)v.x; hi[1] = (_Float16)v.y;
    hi[2] = (_Float16)v.z; hi[3] = (_Float16)v.w;
    lo[0] = (_Float16)((v.x - (float)hi[0]) * 2048.0f);
    lo[1] = (_Float16)((v.y - (float)hi[1]) * 2048.0f);
    lo[2] = (_Float16)((v.z - (float)hi[2]) * 2048.0f);
    lo[3] = (_Float16)((v.w - (float)hi[3]) * 2048.0f);

    if (is_e) {
        int code = (int)(off >> 7);                 // sec*8 + (tid>>5)
        int c = (tid & 31) * 4;
        int tile = code >> 6, w = code & 63;
        int slot = (c >> 3) ^ (w & 15);
        size_t dst = (size_t)tile * 8192 + w * 128 + slot * 8 + (c & 7);
        *(f16x4*)((_Float16*)(wsb + ERH_OFF) + dst) = hi;
        *(f16x4*)((_Float16*)(wsb + ERL_OFF) + dst) = lo;

        float s = v.x * v.x + v.y * v.y + v.z * v.z + v.w * v.w;
        for (int o = 16; o > 0; o >>= 1) s += __shfl_down(s, o, 32);
        if ((tid & 31) == 0)
            ((float*)(wsb + HN_OFF))[code] = 0.5f * s;
    } else {
        _Float16* ph = (_Float16*)(wsb + XRH_OFF);
        _Float16* pl = (_Float16*)(wsb + XRL_OFF);
        *(f16x4*)(ph + off) = hi;
        *(f16x4*)(pl + off) = lo;
        if (sec < 32)
            ((unsigned long long*)(wsb + BEST_OFF))[sec * 256 + tid] = 0ull;
    }
}

// K2: wave-specialized producer/consumer. 320-thread blocks:
//   waves 0-3 (compute): MFMA argmax, vmcnt tracks ONLY the 8 glls/tile ->
//                        vmcnt(0)+barrier is L2-cheap.
//   wave 4 (fill):       issues the block's 32 KB/tile of enc-zero stores and
//                        hits a RAW s_barrier with NO waitcnt -> store
//                        completion (HBM-throttled) leaves the critical path.
// vmcnt is in-order, so mixing stores+glls in one wave forces store-drain at
// every barrier (r0-r4: k2 = SUM of pipes). Specialization makes it a MAX.
__global__ __launch_bounds__(320, 3) void k2_mfma(char* __restrict__ wsb,
                                                  float* __restrict__ out) {
    __shared__ _Float16 lds_e[2][2][8192];   // [buf][hi/lo][64*128] = 64 KB
    __shared__ float    lds_hn[1024];        // 4 KB

    const _Float16* xrh = (const _Float16*)(wsb + XRH_OFF);
    const _Float16* xrl = (const _Float16*)(wsb + XRL_OFF);
    const float* hn = (const float*)(wsb + HN_OFF);
    unsigned long long* bestg = (unsigned long long*)(wsb + BEST_OFF);

    int tid = threadIdx.x;
    int lane = tid & 63, wave = tid >> 6;
    int col = lane & 31, half = lane >> 5;
    int m = blockIdx.x;
    int by = m & 7, bx = m >> 3;             // XCD-pin: same-XCD blocks share by
    int r0 = bx * 128;
    int k0g = by * 1024;

    // staging role (compute waves): wave 0,1 -> hi plane, wave 2,3 -> lo
    int plane = (wave >> 1) & 1;
    int i0 = (wave & 1) * 8;
    const char* pbase = (const char*)wsb + (plane ? ERL_OFF : ERH_OFF);

    f16x8 ah[8], al[8];
    if (wave < 4) {
        int row = r0 + wave * 32 + col;      // A-operand m = lane&31
        #pragma unroll
        for (int s = 0; s < 8; s++) {
            ah[s] = *(const f16x8*)(xrh + (size_t)row * 128 + s * 16 + half * 8);
            al[s] = *(const f16x8*)(xrl + (size_t)row * 128 + s * 16 + half * 8);
        }
        // stage this chunk's half-norms (1024 fp32, tids 0..255)
        *(float4*)(lds_hn + tid * 4) = *(const float4*)(hn + k0g + tid * 4);
        // prologue: stage tile 0 into buf 0
        const char* pb = pbase + (size_t)k0g * 256;
        #pragma unroll
        for (int j = 0; j < 8; j++) {
            int idx = i0 + j;
            gll16(pb + idx * 1024 + lane * 16,
                  (char*)&lds_e[0][plane][0] + idx * 1024);
        }
    }
    __syncthreads();                          // barrier #0 (all 5 waves)

    if (wave == 4) {
        // ---- fill wave: 16 tiles x 32 store-instrs (32 KB), no waitcnt ----
        f32x4v z4 = {0.f, 0.f, 0.f, 0.f};
        f32x4v* dst = (f32x4v*)(out + OUT_ENC) +
                      (long)(by * 64 + bx) * 32768 + lane;
        for (int t = 0; t < 16; t++) {
            #pragma unroll
            for (int i = 0; i < 32; i++)
                dst[t * 2048 + i * 64] = z4;
            __builtin_amdgcn_s_barrier();     // barriers #1..#16, NO drain
        }
        return;                               // exited wave can't block barriers
    }

    float best[16];
    int bidx[16];
    #pragma unroll
    for (int i = 0; i < 16; i++) { best[i] = -3.0e38f; bidx[i] = 0; }

    int b = 0;
    for (int t = 0; t < 16; t++) {
        // (A) issue async prefetch of tile t+1 into buf b^1
        if (t < 15) {
            const char* pb = pbase + (size_t)(k0g + (t + 1) * 64) * 256;
            #pragma unroll
            for (int j = 0; j < 8; j++) {
                int idx = i0 + j;
                gll16(pb + idx * 1024 + lane * 16,
                      (char*)&lds_e[b ^ 1][plane][0] + idx * 1024);
            }
        }

        // (B) compute on buf b (staged last iteration, barrier'd)
        #pragma unroll
        for (int sub = 0; sub < 2; sub++) {
            f32x16 a0, a1, a2;
            #pragma unroll
            for (int i = 0; i < 16; i++) { a0[i] = 0.f; a1[i] = 0.f; a2[i] = 0.f; }
            int cb = (sub * 32 + col) * 128;  // B n-index = lane&31
            #pragma unroll
            for (int s = 0; s < 8; s++) {
                int so = ((s * 2 + half) ^ (col & 15)) * 8;
                f16x8 bh = *(const f16x8*)(&lds_e[b][0][cb + so]);
                f16x8 bl = *(const f16x8*)(&lds_e[b][1][cb + so]);
                a0 = __builtin_amdgcn_mfma_f32_32x32x16_f16(ah[s], bh, a0, 0, 0, 0);
                a1 = __builtin_amdgcn_mfma_f32_32x32x16_f16(ah[s], bl, a1, 0, 0, 0);
                a2 = __builtin_amdgcn_mfma_f32_32x32x16_f16(al[s], bh, a2, 0, 0, 0);
            }
            int code = k0g + t * 64 + sub * 32 + col;
            float hnv = lds_hn[t * 64 + sub * 32 + col];
            #pragma unroll
            for (int r = 0; r < 16; r++) {
                float sc = a0[r] + (a1[r] + a2[r]) * (1.0f / 2048.0f) - hnv;
                if (sc > best[r]) { best[r] = sc; bidx[r] = code; } // > keeps first
            }
        }

        // (C) drain ONLY this wave's glls (L2-resident, cheap), then barrier
        asm volatile("s_waitcnt vmcnt(0)" ::: "memory");
        __builtin_amdgcn_s_barrier();         // barriers #1..#16
        asm volatile("" ::: "memory");
        b ^= 1;
    }

    // reduce across the 32 cols (same half-wave), then device atomicMax.
    // C/D row = (r&3) + 8*(r>>2) + 4*half ; col = lane&31.
    #pragma unroll
    for (int r = 0; r < 16; r++) {
        float s = best[r];
        int bi = bidx[r];
        #pragma unroll
        for (int mm = 1; mm < 32; mm <<= 1) {
            float qs = __shfl_xor(s, mm, 64);
            int qi = __shfl_xor(bi, mm, 64);
            if (qs > s || (qs == s && qi < bi)) { s = qs; bi = qi; }
        }
        if (col == 0) {
            int rl = (r & 3) + 8 * (r >> 2) + 4 * half;
            unsigned ub = __float_as_uint(s);
            ub = ((int)ub < 0) ? ~ub : (ub | 0x80000000u);   // sortable map
            unsigned long long p = ((unsigned long long)ub << 32) |
                                   (unsigned long long)(0xFFFFFFFFu - (unsigned)bi);
            atomicMax(&bestg[r0 + wave * 32 + rl], p);       // tie -> min idx
        }
    }
}

// K3: decode packed best, write one-hot 1.0, gather e[bi] -> NCHW output.
// 128 blocks: 4-way channel split per n.
__global__ __launch_bounds__(256) void k3_final(const char* __restrict__ wsb,
                                                const float* __restrict__ wgt,
                                                float* __restrict__ out) {
    int bid = blockIdx.x;
    int n = (bid & 31) * 256 + threadIdx.x;   // 0..8191
    int q = bid >> 5;                          // channel quarter 0..3
    unsigned long long p = ((const unsigned long long*)(wsb + BEST_OFF))[n];
    int bi = (int)(0xFFFFFFFFu - (unsigned)(p & 0xFFFFFFFFull));

    if (q == 0)
        out[(size_t)OUT_ENC + (size_t)n * 8192 + bi] = 1.0f;

    // out0[((bq*128 + c)*32 + h)*32 + w], n = bq*1024 + h*32 + w
    int bq = n >> 10, hw = n & 1023;
    float* o = out + (size_t)bq * 131072 + hw + (size_t)q * 32 * 1024;
    const float4* wrow = (const float4*)(wgt + (size_t)bi * 128) + q * 8;
    #pragma unroll
    for (int c4 = 0; c4 < 8; c4++) {
        float4 v = wrow[c4];
        o[(c4 * 4 + 0) * 1024] = v.x;
        o[(c4 * 4 + 1) * 1024] = v.y;
        o[(c4 * 4 + 2) * 1024] = v.z;
        o[(c4 * 4 + 3) * 1024] = v.w;
    }
}

extern "C" void kernel_launch(void* const* d_in, const int* in_sizes, int n_in,
                              void* d_out, int out_size, void* d_ws, size_t ws_size,
                              hipStream_t stream) {
    const float* x = (const float*)d_in[0];   // [8,32,32,128] -> [8192][128]
    const float* e = (const float*)d_in[1];   // [8192][128]
    float* out = (float*)d_out;
    char* ws = (char*)d_ws;

    k1_convert<<<2048, 256, 0, stream>>>(x, e, ws);
    k2_mfma<<<512, 320, 0, stream>>>(ws, out);
    k3_final<<<128, 256, 0, stream>>>(ws, e, out);
}

// Round 6
// 334.715 us; speedup vs baseline: 1.0228x; 1.0228x over previous
//
#include <hip/hip_runtime.h>

typedef _Float16 f16x4 __attribute__((ext_vector_type(4)));
typedef _Float16 f16x8 __attribute__((ext_vector_type(8)));
typedef float    f32x16 __attribute__((ext_vector_type(16)));
typedef float    f32x4v __attribute__((ext_vector_type(4)));

// ---- ws byte offsets (total 8,486,912 B) ----
#define HN_OFF   0u                      // 8192 fp32: 0.5*||e||^2   (32 KB)
#define BEST_OFF 32768u                  // 8192 u64 packed best     (64 KB)
#define ERH_OFF  98304u                  // e-hi, TILED+SWIZZLED     (2 MB)
#define ERL_OFF  (98304u + 2097152u)     // e-lo * 2^11, same layout
#define XRH_OFF  (98304u + 2u * 2097152u) // x-hi, row-major
#define XRL_OFF  (98304u + 3u * 2097152u) // x-lo * 2^11, row-major

// ---- out layout (float indices): [quantized NCHW 1M][encodings 64M] ----
#define OUT_Q    0
#define OUT_ENC  1048576

// e-plane DRAM layout = k2's LDS image: 128 tiles of 64 codes; within a tile,
// f16 elem (w, c) stored at tile*8192 + w*128 + ((c>>3) ^ (w&15))*8 + (c&7).
// Bakes the bank-conflict XOR swizzle into DRAM so global_load_lds can stage
// with a LINEAR wave-uniform destination (rule #21 / m173).

__device__ __forceinline__ void gll16(const void* g, void* l) {
    __builtin_amdgcn_global_load_lds(
        (const __attribute__((address_space(1))) unsigned int*)g,
        (__attribute__((address_space(3))) unsigned int*)l, 16, 0, 0);
}

// K1: grid 3072.
//   blocks 0..2047   : split x,e into f16 hi + scaled-lo planes (e pre-swizzled
//                      tile-image); fused 0.5*||e||^2; zero-init packed-best.
//   blocks 2048..3071: zero 256 KB each of the encodings output (256 MB total).
// Fill rides as INDEPENDENT blocks (no LDS, no residency cap, no barriers
// shared with compute) — store completion never gates anyone's vmcnt.
__global__ __launch_bounds__(256) void k1_convert(const float* __restrict__ x,
                                                  const float* __restrict__ e,
                                                  char* __restrict__ wsb,
                                                  float* __restrict__ out) {
    int bx = blockIdx.x, tid = threadIdx.x;

    if (bx >= 2048) {
        // ---- enc zero-fill role: 256 KB/block, plain coalesced stores ----
        int f = bx - 2048;
        f32x4v z4 = {0.f, 0.f, 0.f, 0.f};
        f32x4v* dst = (f32x4v*)(out + OUT_ENC) + (size_t)f * 16384 + tid;
        #pragma unroll 8
        for (int i = 0; i < 64; i++)
            dst[i * 256] = z4;
        return;
    }

    bool is_e = bx < 1024;
    const float* src = is_e ? e : x;
    int sec = is_e ? bx : bx - 1024;
    size_t off = (size_t)sec * 1024 + tid * 4;      // float-element offset
    float4 v = *(const float4*)(src + off);

    f16x4 hi, lo;
    hi[0] = (_Float16)v.x; hi[1] = (_Float16)v.y;
    hi[2] = (_Float16)v.z; hi[3] = (_Float16)v.w;
    lo[0] = (_Float16)((v.x - (float)hi[0]) * 2048.0f);
    lo[1] = (_Float16)((v.y - (float)hi[1]) * 2048.0f);
    lo[2] = (_Float16)((v.z - (float)hi[2]) * 2048.0f);
    lo[3] = (_Float16)((v.w - (float)hi[3]) * 2048.0f);

    if (is_e) {
        int code = (int)(off >> 7);                 // sec*8 + (tid>>5)
        int c = (tid & 31) * 4;
        int tile = code >> 6, w = code & 63;
        int slot = (c >> 3) ^ (w & 15);
        size_t dst = (size_t)tile * 8192 + w * 128 + slot * 8 + (c & 7);
        *(f16x4*)((_Float16*)(wsb + ERH_OFF) + dst) = hi;
        *(f16x4*)((_Float16*)(wsb + ERL_OFF) + dst) = lo;

        float s = v.x * v.x + v.y * v.y + v.z * v.z + v.w * v.w;
        for (int o = 16; o > 0; o >>= 1) s += __shfl_down(s, o, 32);
        if ((tid & 31) == 0)
            ((float*)(wsb + HN_OFF))[code] = 0.5f * s;
    } else {
        _Float16* ph = (_Float16*)(wsb + XRH_OFF);
        _Float16* pl = (_Float16*)(wsb + XRL_OFF);
        *(f16x4*)(ph + off) = hi;
        *(f16x4*)(pl + off) = lo;
        if (sec < 32)
            ((unsigned long long*)(wsb + BEST_OFF))[sec * 256 + tid] = 0ull;
    }
}

// K2: PURE compute (no global stores in the loop). 3-product f16-split MFMA
// argmax, 512 blocks x 4 waves, double-buffered gll staging, plain
// __syncthreads per tile (drains only the 8 L2-resident glls -> cheap).
// r0-r5 lesson: vmcnt retires IN ORDER, so any fused store interleaved with
// glls puts HBM store-completion on every barrier's critical path.
__global__ __launch_bounds__(256, 2) void k2_mfma(char* __restrict__ wsb) {
    __shared__ _Float16 lds_e[2][2][8192];   // [buf][hi/lo][64*128] = 64 KB
    __shared__ float    lds_hn[1024];        // 4 KB

    const _Float16* xrh = (const _Float16*)(wsb + XRH_OFF);
    const _Float16* xrl = (const _Float16*)(wsb + XRL_OFF);
    const float* hn = (const float*)(wsb + HN_OFF);
    unsigned long long* bestg = (unsigned long long*)(wsb + BEST_OFF);

    int tid = threadIdx.x;
    int lane = tid & 63, wave = tid >> 6;
    int col = lane & 31, half = lane >> 5;
    int m = blockIdx.x;
    int by = m & 7, bx = m >> 3;             // XCD-pin: same-XCD blocks share by
    int r0 = bx * 128;
    int k0g = by * 1024;
    int row = r0 + wave * 32 + col;          // A-operand m = lane&31

    // A fragments in registers for the whole kernel (row-major x planes)
    f16x8 ah[8], al[8];
    #pragma unroll
    for (int s = 0; s < 8; s++) {
        ah[s] = *(const f16x8*)(xrh + (size_t)row * 128 + s * 16 + half * 8);
        al[s] = *(const f16x8*)(xrl + (size_t)row * 128 + s * 16 + half * 8);
    }

    // stage this chunk's half-norms (1024 fp32)
    *(float4*)(lds_hn + tid * 4) = *(const float4*)(hn + k0g + tid * 4);

    // staging role: wave 0,1 -> hi plane, wave 2,3 -> lo plane; 8 KB each
    int plane = wave >> 1;
    int i0 = (wave & 1) * 8;
    const char* pbase = (const char*)wsb + (plane ? ERL_OFF : ERH_OFF);

    // prologue: stage tile 0 into buf 0 (tile byte base = (k0g + t*64)*256)
    {
        const char* pb = pbase + (size_t)k0g * 256;
        #pragma unroll
        for (int j = 0; j < 8; j++) {
            int idx = i0 + j;
            gll16(pb + idx * 1024 + lane * 16,
                  (char*)&lds_e[0][plane][0] + idx * 1024);
        }
    }
    __syncthreads();                          // tile 0 + hn visible

    float best[16];
    int bidx[16];
    #pragma unroll
    for (int i = 0; i < 16; i++) { best[i] = -3.0e38f; bidx[i] = 0; }

    int b = 0;
    for (int t = 0; t < 16; t++) {
        // (A) issue async prefetch of tile t+1 into buf b^1
        if (t < 15) {
            const char* pb = pbase + (size_t)(k0g + (t + 1) * 64) * 256;
            #pragma unroll
            for (int j = 0; j < 8; j++) {
                int idx = i0 + j;
                gll16(pb + idx * 1024 + lane * 16,
                      (char*)&lds_e[b ^ 1][plane][0] + idx * 1024);
            }
        }

        // (B) compute on buf b (staged last iteration, barrier'd)
        #pragma unroll
        for (int sub = 0; sub < 2; sub++) {
            f32x16 a0, a1, a2;
            #pragma unroll
            for (int i = 0; i < 16; i++) { a0[i] = 0.f; a1[i] = 0.f; a2[i] = 0.f; }
            int cb = (sub * 32 + col) * 128;  // B n-index = lane&31
            #pragma unroll
            for (int s = 0; s < 8; s++) {
                int so = ((s * 2 + half) ^ (col & 15)) * 8;
                f16x8 bh = *(const f16x8*)(&lds_e[b][0][cb + so]);
                f16x8 bl = *(const f16x8*)(&lds_e[b][1][cb + so]);
                a0 = __builtin_amdgcn_mfma_f32_32x32x16_f16(ah[s], bh, a0, 0, 0, 0);
                a1 = __builtin_amdgcn_mfma_f32_32x32x16_f16(ah[s], bl, a1, 0, 0, 0);
                a2 = __builtin_amdgcn_mfma_f32_32x32x16_f16(al[s], bh, a2, 0, 0, 0);
            }
            int code = k0g + t * 64 + sub * 32 + col;
            float hnv = lds_hn[t * 64 + sub * 32 + col];
            #pragma unroll
            for (int r = 0; r < 16; r++) {
                float sc = a0[r] + (a1[r] + a2[r]) * (1.0f / 2048.0f) - hnv;
                if (sc > best[r]) { best[r] = sc; bidx[r] = code; } // > keeps first
            }
        }

        // (C) barrier: drains only this wave's 8 glls (L2-resident, cheap)
        __syncthreads();
        b ^= 1;
    }

    // reduce across the 32 cols (same half-wave), then device atomicMax.
    // C/D row = (r&3) + 8*(r>>2) + 4*half ; col = lane&31.
    #pragma unroll
    for (int r = 0; r < 16; r++) {
        float s = best[r];
        int bi = bidx[r];
        #pragma unroll
        for (int mm = 1; mm < 32; mm <<= 1) {
            float qs = __shfl_xor(s, mm, 64);
            int qi = __shfl_xor(bi, mm, 64);
            if (qs > s || (qs == s && qi < bi)) { s = qs; bi = qi; }
        }
        if (col == 0) {
            int rl = (r & 3) + 8 * (r >> 2) + 4 * half;
            unsigned ub = __float_as_uint(s);
            ub = ((int)ub < 0) ? ~ub : (ub | 0x80000000u);   // sortable map
            unsigned long long p = ((unsigned long long)ub << 32) |
                                   (unsigned long long)(0xFFFFFFFFu - (unsigned)bi);
            atomicMax(&bestg[r0 + wave * 32 + rl], p);       // tie -> min idx
        }
    }
}

// K3: decode packed best, write one-hot 1.0, gather e[bi] -> NCHW output.
// 128 blocks: 4-way channel split per n.
__global__ __launch_bounds__(256) void k3_final(const char* __restrict__ wsb,
                                                const float* __restrict__ wgt,
                                                float* __restrict__ out) {
    int bid = blockIdx.x;
    int n = (bid & 31) * 256 + threadIdx.x;   // 0..8191
    int q = bid >> 5;                          // channel quarter 0..3
    unsigned long long p = ((const unsigned long long*)(wsb + BEST_OFF))[n];
    int bi = (int)(0xFFFFFFFFu - (unsigned)(p & 0xFFFFFFFFull));

    if (q == 0)
        out[(size_t)OUT_ENC + (size_t)n * 8192 + bi] = 1.0f;

    // out0[((bq*128 + c)*32 + h)*32 + w], n = bq*1024 + h*32 + w
    int bq = n >> 10, hw = n & 1023;
    float* o = out + (size_t)bq * 131072 + hw + (size_t)q * 32 * 1024;
    const float4* wrow = (const float4*)(wgt + (size_t)bi * 128) + q * 8;
    #pragma unroll
    for (int c4 = 0; c4 < 8; c4++) {
        float4 v = wrow[c4];
        o[(c4 * 4 + 0) * 1024] = v.x;
        o[(c4 * 4 + 1) * 1024] = v.y;
        o[(c4 * 4 + 2) * 1024] = v.z;
        o[(c4 * 4 + 3) * 1024] = v.w;
    }
}

extern "C" void kernel_launch(void* const* d_in, const int* in_sizes, int n_in,
                              void* d_out, int out_size, void* d_ws, size_t ws_size,
                              hipStream_t stream) {
    const float* x = (const float*)d_in[0];   // [8,32,32,128] -> [8192][128]
    const float* e = (const float*)d_in[1];   // [8192][128]
    float* out = (float*)d_out;
    char* ws = (char*)d_ws;

    k1_convert<<<3072, 256, 0, stream>>>(x, e, ws, out);
    k2_mfma<<<512, 256, 0, stream>>>(ws);
    k3_final<<<128, 256, 0, stream>>>(ws, e, out);
}

// Round 7
// 329.523 us; speedup vs baseline: 1.0389x; 1.0158x over previous
//
#include <hip/hip_runtime.h>

typedef _Float16 f16x4 __attribute__((ext_vector_type(4)));
typedef _Float16 f16x8 __attribute__((ext_vector_type(8)));
typedef float    f32x16 __attribute__((ext_vector_type(16)));
typedef float    f32x4v __attribute__((ext_vector_type(4)));

// ---- ws byte offsets (total 8,486,912 B) ----
#define HN_OFF   0u                      // 8192 fp32: 0.5*||e||^2   (32 KB)
#define BEST_OFF 32768u                  // 8192 u64 packed best     (64 KB)
#define ERH_OFF  98304u                  // e-hi, FRAG-MAJOR         (2 MB)
#define ERL_OFF  (98304u + 2097152u)     // e-lo * 2^11, same layout
#define XRH_OFF  (98304u + 2u * 2097152u) // x-hi, row-major
#define XRL_OFF  (98304u + 3u * 2097152u) // x-lo * 2^11, row-major

// ---- out layout (float indices): [quantized NCHW 1M][encodings 64M] ----
#define OUT_Q    0
#define OUT_ENC  1048576

// e-plane DRAM layout = FRAG-MAJOR (r6 lesson: drop LDS entirely; e is
// L2-resident per XCD, and all 4 waves read identical fragments -> L1 dedup).
// f16 elem (code w, channel c) of tile T (64 codes):
//   s = c>>4, half = (c>>3)&1  ->  B-fragment k-slice of mfma_32x32x16
//   addr = T*8192 + s*1024 + w*16 + half*8 + (c&7)     (elems)
// A wave's B-load for (s, sub): lanes l=0..63 read w=sub*32+(l&31),
// half=l>>5 -> 1 KB CONTIGUOUS per load instr (perfect coalescing).

// K1: split x,e into f16 hi + scaled-lo planes; e-planes written frag-major;
// fused 0.5*||e||^2; zero-init packed-best array.
__global__ __launch_bounds__(256) void k1_convert(const float* __restrict__ x,
                                                  const float* __restrict__ e,
                                                  char* __restrict__ wsb) {
    int bx = blockIdx.x, tid = threadIdx.x;
    bool is_e = bx < 1024;
    const float* src = is_e ? e : x;
    int sec = is_e ? bx : bx - 1024;
    size_t off = (size_t)sec * 1024 + tid * 4;      // float-element offset
    float4 v = *(const float4*)(src + off);

    f16x4 hi, lo;
    hi[0] = (_Float16)v.x; hi[1] = (_Float16)v.y;
    hi[2] = (_Float16)v.z; hi[3] = (_Float16)v.w;
    lo[0] = (_Float16)((v.x - (float)hi[0]) * 2048.0f);
    lo[1] = (_Float16)((v.y - (float)hi[1]) * 2048.0f);
    lo[2] = (_Float16)((v.z - (float)hi[2]) * 2048.0f);
    lo[3] = (_Float16)((v.w - (float)hi[3]) * 2048.0f);

    if (is_e) {
        int code = (int)(off >> 7);                 // sec*8 + (tid>>5)
        int c = (tid & 31) * 4;                     // 4 consecutive channels
        int tile = code >> 6, w = code & 63;
        int s = c >> 4, half = (c >> 3) & 1;
        size_t dst = (size_t)tile * 8192 + s * 1024 + w * 16 + half * 8 + (c & 7);
        *(f16x4*)((_Float16*)(wsb + ERH_OFF) + dst) = hi;
        *(f16x4*)((_Float16*)(wsb + ERL_OFF) + dst) = lo;

        float ss = v.x * v.x + v.y * v.y + v.z * v.z + v.w * v.w;
        for (int o = 16; o > 0; o >>= 1) ss += __shfl_down(ss, o, 32);
        if ((tid & 31) == 0)
            ((float*)(wsb + HN_OFF))[code] = 0.5f * ss;
    } else {
        _Float16* ph = (_Float16*)(wsb + XRH_OFF);
        _Float16* pl = (_Float16*)(wsb + XRL_OFF);
        *(f16x4*)(ph + off) = hi;
        *(f16x4*)(pl + off) = lo;
        if (sec < 32)
            ((unsigned long long*)(wsb + BEST_OFF))[sec * 256 + tid] = 0ull;
    }
}

// K2: BARRIER-FREE direct-load MFMA argmax + fused enc zero-fill.
// No __shared__, no __syncthreads, no global_load_lds: B-fragments load
// straight from the frag-major e-planes (L2-resident/XCD, L1-dedup across
// the 4 waves). Pure dataflow -> compiler software-pipelines the t-loop.
// Fill stores are issued AFTER each sub's loads, so compiler load-waits
// vmcnt(N) never force store retirement (in-order ledger: stores newest).
__global__ __launch_bounds__(256, 2) void k2_mfma(char* __restrict__ wsb,
                                                  float* __restrict__ out) {
    const _Float16* xrh = (const _Float16*)(wsb + XRH_OFF);
    const _Float16* xrl = (const _Float16*)(wsb + XRL_OFF);
    const _Float16* erh = (const _Float16*)(wsb + ERH_OFF);
    const _Float16* erl = (const _Float16*)(wsb + ERL_OFF);
    const float* hn = (const float*)(wsb + HN_OFF);
    unsigned long long* bestg = (unsigned long long*)(wsb + BEST_OFF);

    int tid = threadIdx.x;
    int lane = tid & 63, wave = tid >> 6;
    int col = lane & 31, half = lane >> 5;
    int m = blockIdx.x;
    int by = m & 7, bx = m >> 3;             // XCD-pin: same-XCD blocks share by
    int r0 = bx * 128;
    int k0g = by * 1024;
    int row = r0 + wave * 32 + col;          // A-operand m = lane&31

    // A fragments in registers for the whole kernel (row-major x planes)
    f16x8 ah[8], al[8];
    #pragma unroll
    for (int s = 0; s < 8; s++) {
        ah[s] = *(const f16x8*)(xrh + (size_t)row * 128 + s * 16 + half * 8);
        al[s] = *(const f16x8*)(xrl + (size_t)row * 128 + s * 16 + half * 8);
    }

    // per-lane element offset inside a (tile, s, sub) fragment slab
    int lane_eo = col * 16 + half * 8;
    const _Float16* phz = erh + (size_t)(k0g >> 6) * 8192;  // tile base, t=0
    const _Float16* plz = erl + (size_t)(k0g >> 6) * 8192;

    float best[16];
    int bidx[16];
    #pragma unroll
    for (int i = 0; i < 16; i++) { best[i] = -3.0e38f; bidx[i] = 0; }

    // fused enc zero-fill: this block owns 512 KB; 8 f32x4 stores per sub
    f32x4v z4 = {0.f, 0.f, 0.f, 0.f};
    f32x4v* dstf = (f32x4v*)(out + OUT_ENC) + (size_t)(by * 64 + bx) * 32768 + tid;

    for (int t = 0; t < 16; t++) {
        const _Float16* ph = phz + (size_t)t * 8192;
        const _Float16* pl = plz + (size_t)t * 8192;
        #pragma unroll
        for (int sub = 0; sub < 2; sub++) {
            f32x16 a0, a1, a2;
            #pragma unroll
            for (int i = 0; i < 16; i++) { a0[i] = 0.f; a1[i] = 0.f; a2[i] = 0.f; }
            const _Float16* phs = ph + sub * 512 + lane_eo;
            const _Float16* pls = pl + sub * 512 + lane_eo;
            #pragma unroll
            for (int s = 0; s < 8; s++) {
                f16x8 bh = *(const f16x8*)(phs + s * 1024);
                f16x8 bl = *(const f16x8*)(pls + s * 1024);
                a0 = __builtin_amdgcn_mfma_f32_32x32x16_f16(ah[s], bh, a0, 0, 0, 0);
                a1 = __builtin_amdgcn_mfma_f32_32x32x16_f16(ah[s], bl, a1, 0, 0, 0);
                a2 = __builtin_amdgcn_mfma_f32_32x32x16_f16(al[s], bh, a2, 0, 0, 0);
            }
            // fill stores: after the loads (ledger: stores newest -> load
            // waits never retire them; they drain in background to kernel end)
            #pragma unroll
            for (int i = 0; i < 4; i++)
                dstf[(t * 2 + sub) * 1024 + i * 256] = z4;

            int code = k0g + t * 64 + sub * 32 + col;
            float hnv = hn[code];
            #pragma unroll
            for (int r = 0; r < 16; r++) {
                float sc = a0[r] + (a1[r] + a2[r]) * (1.0f / 2048.0f) - hnv;
                if (sc > best[r]) { best[r] = sc; bidx[r] = code; } // > keeps first
            }
        }
    }

    // reduce across the 32 cols (same half-wave), then device atomicMax.
    // C/D row = (r&3) + 8*(r>>2) + 4*half ; col = lane&31.
    #pragma unroll
    for (int r = 0; r < 16; r++) {
        float s = best[r];
        int bi = bidx[r];
        #pragma unroll
        for (int mm = 1; mm < 32; mm <<= 1) {
            float qs = __shfl_xor(s, mm, 64);
            int qi = __shfl_xor(bi, mm, 64);
            if (qs > s || (qs == s && qi < bi)) { s = qs; bi = qi; }
        }
        if (col == 0) {
            int rl = (r & 3) + 8 * (r >> 2) + 4 * half;
            unsigned ub = __float_as_uint(s);
            ub = ((int)ub < 0) ? ~ub : (ub | 0x80000000u);   // sortable map
            unsigned long long p = ((unsigned long long)ub << 32) |
                                   (unsigned long long)(0xFFFFFFFFu - (unsigned)bi);
            atomicMax(&bestg[r0 + wave * 32 + rl], p);       // tie -> min idx
        }
    }
}

// K3: decode packed best, write one-hot 1.0, gather e[bi] -> NCHW output.
// 128 blocks: 4-way channel split per n.
__global__ __launch_bounds__(256) void k3_final(const char* __restrict__ wsb,
                                                const float* __restrict__ wgt,
                                                float* __restrict__ out) {
    int bid = blockIdx.x;
    int n = (bid & 31) * 256 + threadIdx.x;   // 0..8191
    int q = bid >> 5;                          // channel quarter 0..3
    unsigned long long p = ((const unsigned long long*)(wsb + BEST_OFF))[n];
    int bi = (int)(0xFFFFFFFFu - (unsigned)(p & 0xFFFFFFFFull));

    if (q == 0)
        out[(size_t)OUT_ENC + (size_t)n * 8192 + bi] = 1.0f;

    // out0[((bq*128 + c)*32 + h)*32 + w], n = bq*1024 + h*32 + w
    int bq = n >> 10, hw = n & 1023;
    float* o = out + (size_t)bq * 131072 + hw + (size_t)q * 32 * 1024;
    const float4* wrow = (const float4*)(wgt + (size_t)bi * 128) + q * 8;
    #pragma unroll
    for (int c4 = 0; c4 < 8; c4++) {
        float4 v = wrow[c4];
        o[(c4 * 4 + 0) * 1024] = v.x;
        o[(c4 * 4 + 1) * 1024] = v.y;
        o[(c4 * 4 + 2) * 1024] = v.z;
        o[(c4 * 4 + 3) * 1024] = v.w;
    }
}

extern "C" void kernel_launch(void* const* d_in, const int* in_sizes, int n_in,
                              void* d_out, int out_size, void* d_ws, size_t ws_size,
                              hipStream_t stream) {
    const float* x = (const float*)d_in[0];   // [8,32,32,128] -> [8192][128]
    const float* e = (const float*)d_in[1];   // [8192][128]
    float* out = (float*)d_out;
    char* ws = (char*)d_ws;

    k1_convert<<<2048, 256, 0, stream>>>(x, e, ws);
    k2_mfma<<<512, 256, 0, stream>>>(ws, out);
    k3_final<<<128, 256, 0, stream>>>(ws, e, out);
}

// Round 8
// 325.816 us; speedup vs baseline: 1.0507x; 1.0114x over previous
//
#include <hip/hip_runtime.h>

typedef _Float16 f16x4 __attribute__((ext_vector_type(4)));
typedef _Float16 f16x8 __attribute__((ext_vector_type(8)));
typedef float    f32x16 __attribute__((ext_vector_type(16)));
typedef float    f32x4v __attribute__((ext_vector_type(4)));

// ---- ws byte offsets (total 8,486,912 B) ----
#define HN_OFF   0u                      // 8192 fp32: 0.5*||e||^2   (32 KB)
#define BEST_OFF 32768u                  // 8192 u64 packed best     (64 KB)
#define ERH_OFF  98304u                  // e-hi, A-FRAG-TILED       (2 MB)
#define ERL_OFF  (98304u + 2097152u)     // e-lo * 2^11, same layout
#define XRH_OFF  (98304u + 2u * 2097152u) // x-hi, row-major
#define XRL_OFF  (98304u + 3u * 2097152u) // x-lo * 2^11, row-major

// ---- out layout (float indices): [quantized NCHW 1M][encodings 64M] ----
#define OUT_Q    0
#define OUT_ENC  1048576

// e-plane DRAM layout = A-operand tile image (codes are the MFMA A-operand
// now: swap-trick kills the 4x LDS redundancy — x-rows live in registers,
// shared free; each wave ds_reads only ITS 32-code fragments).
// f16 elem (code w, ch c): T=w>>6, cs=(w>>5)&1, col=w&31, s=c>>4, hf=(c>>3)&1
//   elem addr = T*8192 + cs*4096 + s*512 + hf*256 + col*8 + (c&7)
// A wave's frag read for (cs,s) = 1024 B CONTIGUOUS at lane*16 -> linear
// (= what gll writes; zero bank conflicts, rule #21-clean).

__device__ __forceinline__ void gll16(const void* g, void* l) {
    __builtin_amdgcn_global_load_lds(
        (const __attribute__((address_space(1))) unsigned int*)g,
        (__attribute__((address_space(3))) unsigned int*)l, 16, 0, 0);
}

// K1: split x,e into f16 hi + scaled-lo planes; e-planes written A-frag-tiled;
// fused 0.5*||e||^2; zero-init packed-best array.
__global__ __launch_bounds__(256) void k1_convert(const float* __restrict__ x,
                                                  const float* __restrict__ e,
                                                  char* __restrict__ wsb) {
    int bx = blockIdx.x, tid = threadIdx.x;
    bool is_e = bx < 1024;
    const float* src = is_e ? e : x;
    int sec = is_e ? bx : bx - 1024;
    size_t off = (size_t)sec * 1024 + tid * 4;      // float-element offset
    float4 v = *(const float4*)(src + off);

    f16x4 hi, lo;
    hi[0] = (_Float16)v.x; hi[1] = (_Float16)v.y;
    hi[2] = (_Float16)v.z; hi[3] = (_Float16)v.w;
    lo[0] = (_Float16)((v.x - (float)hi[0]) * 2048.0f);
    lo[1] = (_Float16)((v.y - (float)hi[1]) * 2048.0f);
    lo[2] = (_Float16)((v.z - (float)hi[2]) * 2048.0f);
    lo[3] = (_Float16)((v.w - (float)hi[3]) * 2048.0f);

    if (is_e) {
        int code = (int)(off >> 7);                 // sec*8 + (tid>>5)
        int c = (tid & 31) * 4;                     // 4 consecutive channels
        int T = code >> 6, cs = (code >> 5) & 1, colc = code & 31;
        int s = c >> 4, hf = (c >> 3) & 1;
        size_t dst = (size_t)T * 8192 + cs * 4096 + s * 512 + hf * 256
                   + colc * 8 + (c & 7);
        *(f16x4*)((_Float16*)(wsb + ERH_OFF) + dst) = hi;
        *(f16x4*)((_Float16*)(wsb + ERL_OFF) + dst) = lo;

        float ss = v.x * v.x + v.y * v.y + v.z * v.z + v.w * v.w;
        for (int o = 16; o > 0; o >>= 1) ss += __shfl_down(ss, o, 32);
        if ((tid & 31) == 0)
            ((float*)(wsb + HN_OFF))[code] = 0.5f * ss;
    } else {
        _Float16* ph = (_Float16*)(wsb + XRH_OFF);
        _Float16* pl = (_Float16*)(wsb + XRL_OFF);
        *(f16x4*)(ph + off) = hi;
        *(f16x4*)(pl + off) = lo;
        if (sec < 32)
            ((unsigned long long*)(wsb + BEST_OFF))[sec * 256 + tid] = 0ull;
    }
}

// K2: operand-swapped MFMA argmax + store-only fill wave.
// 1024 blocks x 320 threads (5 waves). Block = 64 rows x 1024 codes.
//   waves 0-3 (compute): wave (rset=w&1, cs=w>>1): rows rset*32+col in REGS
//     (B-operand, 64 VGPR, shared redundancy-free); codes cs*32 per tile from
//     LDS (A-operand, distinct per wave -> LDS traffic / 4 vs m-split).
//     Per-lane state: ONE (best,idx) pair (lane owns one row).
//   wave 4 (fill): issues 256 KB of enc-zero stores, returns immediately —
//     ZERO barriers (exited waves don't count; r5 verified mechanics).
//     Stores overlap compute chip-wide without touching any vmcnt ledger.
// LDS 68 KB -> 2 blocks/CU; VGPR<=170 via (320,3) -> 10 waves/CU place.
__global__ __launch_bounds__(320, 3) void k2_mfma(char* __restrict__ wsb,
                                                  float* __restrict__ out) {
    __shared__ _Float16 lds_e[2][2][8192];   // [buf][hi/lo][64codes*128ch]=64KB
    __shared__ float    lds_hn[1024];        // 4 KB

    const _Float16* xrh = (const _Float16*)(wsb + XRH_OFF);
    const _Float16* xrl = (const _Float16*)(wsb + XRL_OFF);
    const float* hn = (const float*)(wsb + HN_OFF);
    unsigned long long* bestg = (unsigned long long*)(wsb + BEST_OFF);

    int tid = threadIdx.x;
    int lane = tid & 63, wave = tid >> 6;
    int col = lane & 31, half = lane >> 5;
    int m = blockIdx.x;
    int by = m & 7, g = m >> 3;              // XCD-pin: same-XCD share chunk by
    int k0g = by * 1024;
    int r0 = g * 64;

    if (wave == 4) {
        // ---- fill wave: 256 KB enc-zero, no barriers, exit ----
        f32x4v z4 = {0.f, 0.f, 0.f, 0.f};
        f32x4v* dst = (f32x4v*)(out + OUT_ENC) + (size_t)m * 16384 + lane;
        #pragma unroll 4
        for (int i = 0; i < 256; i++)
            dst[i * 64] = z4;
        return;
    }

    int rset = wave & 1, cs = wave >> 1;
    int row = r0 + rset * 32 + col;

    // x-row fragments = MFMA B-operand, persistent registers (64 VGPR)
    f16x8 xh[8], xl[8];
    #pragma unroll
    for (int s = 0; s < 8; s++) {
        xh[s] = *(const f16x8*)(xrh + (size_t)row * 128 + s * 16 + half * 8);
        xl[s] = *(const f16x8*)(xrl + (size_t)row * 128 + s * 16 + half * 8);
    }

    // stage this chunk's half-norms (1024 fp32; tids 0..255 = waves 0-3)
    *(float4*)(lds_hn + tid * 4) = *(const float4*)(hn + k0g + tid * 4);

    // staging role: wave stages plane cs, half-slab rset (8 KB = 8 glls)
    const char* psrc = (const char*)wsb + (cs ? ERL_OFF : ERH_OFF);

    // prologue: stage tile 0 into buf 0 (tile slab = (by*16+t)*16 KB/plane)
    {
        const char* pb = psrc + (size_t)(by * 16) * 16384 + rset * 8192;
        char* ld = (char*)&lds_e[0][cs][0] + rset * 8192;
        #pragma unroll
        for (int j = 0; j < 8; j++)
            gll16(pb + j * 1024 + lane * 16, ld + j * 1024);
    }
    __syncthreads();                          // tile 0 + hn visible

    float best = -3.0e38f;
    int bidx = 0;

    int b = 0;
    for (int t = 0; t < 16; t++) {
        // (A) async prefetch tile t+1 into buf b^1
        if (t < 15) {
            const char* pb = psrc + (size_t)(by * 16 + t + 1) * 16384 + rset * 8192;
            char* ld = (char*)&lds_e[b ^ 1][cs][0] + rset * 8192;
            #pragma unroll
            for (int j = 0; j < 8; j++)
                gll16(pb + j * 1024 + lane * 16, ld + j * 1024);
        }

        // (B) compute: A = this wave's 32 codes (LDS, linear lane*16 reads),
        //     B = 32 x-rows (registers). D[code][row].
        const _Float16* Ah = &lds_e[b][0][cs * 4096 + lane * 8];
        const _Float16* Al = &lds_e[b][1][cs * 4096 + lane * 8];
        f32x16 a0, a1, a2;
        #pragma unroll
        for (int i = 0; i < 16; i++) { a0[i] = 0.f; a1[i] = 0.f; a2[i] = 0.f; }
        #pragma unroll
        for (int s = 0; s < 8; s++) {
            f16x8 eh = *(const f16x8*)(Ah + s * 512);
            f16x8 el = *(const f16x8*)(Al + s * 512);
            a0 = __builtin_amdgcn_mfma_f32_32x32x16_f16(eh, xh[s], a0, 0, 0, 0);
            a1 = __builtin_amdgcn_mfma_f32_32x32x16_f16(el, xh[s], a1, 0, 0, 0);
            a2 = __builtin_amdgcn_mfma_f32_32x32x16_f16(eh, xl[s], a2, 0, 0, 0);
        }
        // D code = (r&3) + 8*(r>>2) + 4*half (ascending in r per lane -> ties
        // resolve to lowest index with strict >); D col = x-row = our `col`.
        int cb = k0g + t * 64 + cs * 32 + 4 * half;
        #pragma unroll
        for (int gq = 0; gq < 4; gq++) {
            float4 h4 = *(const float4*)(lds_hn + t * 64 + cs * 32 + gq * 8 + half * 4);
            #pragma unroll
            for (int j = 0; j < 4; j++) {
                int r = gq * 4 + j;
                float hv = (j == 0) ? h4.x : (j == 1) ? h4.y : (j == 2) ? h4.z : h4.w;
                float sc = a0[r] + (a1[r] + a2[r]) * (1.0f / 2048.0f) - hv;
                int cv = cb + gq * 8 + j;
                if (sc > best) { best = sc; bidx = cv; }
            }
        }

        // (C) barrier: drains only this wave's 8 glls (L2-resident, cheap)
        __syncthreads();
        b ^= 1;
    }

    // merge lane <-> lane^32 (same row, disjoint code subsets), then atomic.
    {
        float qs = __shfl_xor(best, 32, 64);
        int qi = __shfl_xor(bidx, 32, 64);
        if (qs > best || (qs == best && qi < bidx)) { best = qs; bidx = qi; }
        if (half == 0) {
            unsigned ub = __float_as_uint(best);
            ub = ((int)ub < 0) ? ~ub : (ub | 0x80000000u);   // sortable map
            unsigned long long p = ((unsigned long long)ub << 32) |
                                   (unsigned long long)(0xFFFFFFFFu - (unsigned)bidx);
            atomicMax(&bestg[row], p);                        // tie -> min idx
        }
    }
}

// K3: decode packed best, write one-hot 1.0, gather e[bi] -> NCHW output.
// 128 blocks: 4-way channel split per n.
__global__ __launch_bounds__(256) void k3_final(const char* __restrict__ wsb,
                                                const float* __restrict__ wgt,
                                                float* __restrict__ out) {
    int bid = blockIdx.x;
    int n = (bid & 31) * 256 + threadIdx.x;   // 0..8191
    int q = bid >> 5;                          // channel quarter 0..3
    unsigned long long p = ((const unsigned long long*)(wsb + BEST_OFF))[n];
    int bi = (int)(0xFFFFFFFFu - (unsigned)(p & 0xFFFFFFFFull));

    if (q == 0)
        out[(size_t)OUT_ENC + (size_t)n * 8192 + bi] = 1.0f;

    // out0[((bq*128 + c)*32 + h)*32 + w], n = bq*1024 + h*32 + w
    int bq = n >> 10, hw = n & 1023;
    float* o = out + (size_t)bq * 131072 + hw + (size_t)q * 32 * 1024;
    const float4* wrow = (const float4*)(wgt + (size_t)bi * 128) + q * 8;
    #pragma unroll
    for (int c4 = 0; c4 < 8; c4++) {
        float4 v = wrow[c4];
        o[(c4 * 4 + 0) * 1024] = v.x;
        o[(c4 * 4 + 1) * 1024] = v.y;
        o[(c4 * 4 + 2) * 1024] = v.z;
        o[(c4 * 4 + 3) * 1024] = v.w;
    }
}

extern "C" void kernel_launch(void* const* d_in, const int* in_sizes, int n_in,
                              void* d_out, int out_size, void* d_ws, size_t ws_size,
                              hipStream_t stream) {
    const float* x = (const float*)d_in[0];   // [8,32,32,128] -> [8192][128]
    const float* e = (const float*)d_in[1];   // [8192][128]
    float* out = (float*)d_out;
    char* ws = (char*)d_ws;

    k1_convert<<<2048, 256, 0, stream>>>(x, e, ws);
    k2_mfma<<<1024, 320, 0, stream>>>(ws, out);
    k3_final<<<128, 256, 0, stream>>>(ws, e, out);
}

// Round 9
// 310.928 us; speedup vs baseline: 1.1010x; 1.0479x over previous
//
#include <hip/hip_runtime.h>

typedef _Float16 f16x4 __attribute__((ext_vector_type(4)));
typedef _Float16 f16x8 __attribute__((ext_vector_type(8)));
typedef float    f32x16 __attribute__((ext_vector_type(16)));
typedef float    f32x4v __attribute__((ext_vector_type(4)));

// ---- ws byte offsets (total 8,486,912 B) ----
#define HN_OFF   0u                      // 8192 fp32: 0.5*||e||^2   (32 KB)
#define BEST_OFF 32768u                  // 8192 u64 packed best     (64 KB)
#define ERH_OFF  98304u                  // e-hi, A-FRAG-TILED       (2 MB)
#define ERL_OFF  (98304u + 2097152u)     // e-lo * 2^11, same layout
#define XRH_OFF  (98304u + 2u * 2097152u) // x-hi, row-major
#define XRL_OFF  (98304u + 3u * 2097152u) // x-lo * 2^11, row-major

// ---- out layout (float indices): [quantized NCHW 1M][encodings 64M] ----
#define OUT_Q    0
#define OUT_ENC  1048576

// e-plane DRAM layout = A-FRAG-TILED (same as r8's k1; verified passing):
// f16 elem (code w, ch c): T=w>>6, cs=(w>>5)&1, col=w&31, s=c>>4, hf=(c>>3)&1
//   elem addr = T*8192 + cs*4096 + s*512 + hf*256 + col*8 + (c&7)
// A wave's frag (T,cs,s) = bytes [ct*8192 + s*1024, +1024) CONTIGUOUS with
// lane l at +(l>>5)*512 + (l&31)*16, where ct = T*2+cs. Perfect coalescing
// for DIRECT global_load_dwordx4 — no LDS pass-through needed.

// K1: split x,e into f16 hi + scaled-lo planes; e-planes written A-frag-tiled;
// fused 0.5*||e||^2; zero-init packed-best array. (unchanged from r8)
__global__ __launch_bounds__(256) void k1_convert(const float* __restrict__ x,
                                                  const float* __restrict__ e,
                                                  char* __restrict__ wsb) {
    int bx = blockIdx.x, tid = threadIdx.x;
    bool is_e = bx < 1024;
    const float* src = is_e ? e : x;
    int sec = is_e ? bx : bx - 1024;
    size_t off = (size_t)sec * 1024 + tid * 4;      // float-element offset
    float4 v = *(const float4*)(src + off);

    f16x4 hi, lo;
    hi[0] = (_Float16)v.x; hi[1] = (_Float16)v.y;
    hi[2] = (_Float16)v.z; hi[3] = (_Float16)v.w;
    lo[0] = (_Float16)((v.x - (float)hi[0]) * 2048.0f);
    lo[1] = (_Float16)((v.y - (float)hi[1]) * 2048.0f);
    lo[2] = (_Float16)((v.z - (float)hi[2]) * 2048.0f);
    lo[3] = (_Float16)((v.w - (float)hi[3]) * 2048.0f);

    if (is_e) {
        int code = (int)(off >> 7);                 // sec*8 + (tid>>5)
        int c = (tid & 31) * 4;                     // 4 consecutive channels
        int T = code >> 6, cs = (code >> 5) & 1, colc = code & 31;
        int s = c >> 4, hf = (c >> 3) & 1;
        size_t dst = (size_t)T * 8192 + cs * 4096 + s * 512 + hf * 256
                   + colc * 8 + (c & 7);
        *(f16x4*)((_Float16*)(wsb + ERH_OFF) + dst) = hi;
        *(f16x4*)((_Float16*)(wsb + ERL_OFF) + dst) = lo;

        float ss = v.x * v.x + v.y * v.y + v.z * v.z + v.w * v.w;
        for (int o = 16; o > 0; o >>= 1) ss += __shfl_down(ss, o, 32);
        if ((tid & 31) == 0)
            ((float*)(wsb + HN_OFF))[code] = 0.5f * ss;
    } else {
        _Float16* ph = (_Float16*)(wsb + XRH_OFF);
        _Float16* pl = (_Float16*)(wsb + XRL_OFF);
        *(f16x4*)(ph + off) = hi;
        *(f16x4*)(pl + off) = lo;
        if (sec < 32)
            ((unsigned long long*)(wsb + BEST_OFF))[sec * 256 + tid] = 0ull;
    }
}

// K2: ZERO-SYNC direct-load operand-swapped MFMA argmax + fused enc-fill.
// No __shared__, no barriers, no global_load_lds, no inline-asm waits.
// 512 blocks x 256 thr, all co-resident in ONE generation (no LDS bound;
// VGPR-capped 3 waves/SIMD). Each wave: 32 x-rows in regs (B-operand),
// loops 32 code-groups of its chunk, loading ITS OWN 16 KB of A-fragments
// directly from L2 (XCD-pinned 512 KB working set; swap => no redundancy).
// Pure dataflow: compiler software-pipelines loads across iterations and
// 3 waves/SIMD overlap L2 latency, MFMA, and VALU — the first variant with
// no per-tile coupling whatsoever (r0-r8 all summed their pipes serially).
__global__ __launch_bounds__(256, 3) void k2_mfma(char* __restrict__ wsb,
                                                  float* __restrict__ out) {
    const _Float16* xrh = (const _Float16*)(wsb + XRH_OFF);
    const _Float16* xrl = (const _Float16*)(wsb + XRL_OFF);
    const float* hn = (const float*)(wsb + HN_OFF);
    unsigned long long* bestg = (unsigned long long*)(wsb + BEST_OFF);

    int tid = threadIdx.x;
    int lane = tid & 63, wave = tid >> 6;
    int col = lane & 31, half = lane >> 5;
    int m = blockIdx.x;
    int by = m & 7, g = m >> 3;              // XCD-pin: same-XCD share chunk by
    int k0g = by * 1024;
    int row = g * 128 + wave * 32 + col;     // this lane's x-row (D col)

    // x-row fragments = MFMA B-operand, persistent registers (64 VGPR)
    f16x8 xh[8], xl[8];
    #pragma unroll
    for (int s = 0; s < 8; s++) {
        xh[s] = *(const f16x8*)(xrh + (size_t)row * 128 + s * 16 + half * 8);
        xl[s] = *(const f16x8*)(xrl + (size_t)row * 128 + s * 16 + half * 8);
    }

    // chunk base (bytes) in the A-frag-tiled planes; per-lane frag offset
    size_t cbase = (size_t)by * 262144;      // by*16 tiles * 16384 B
    int laneoff = half * 512 + col * 16;
    const char* ph = (const char*)wsb + ERH_OFF + cbase + laneoff;
    const char* pl = (const char*)wsb + ERL_OFF + cbase + laneoff;

    float best = -3.0e38f;
    int bidx = 0;

    // fused enc zero-fill: block m owns bytes [m*512K, +512K) of encodings
    f32x4v z4 = {0.f, 0.f, 0.f, 0.f};
    f32x4v* dstf = (f32x4v*)(out + OUT_ENC) + (size_t)m * 32768 + tid;

    for (int ct = 0; ct < 32; ct++) {        // code-group = (T=ct>>1, cs=ct&1)
        const char* bh = ph + (size_t)ct * 8192;
        const char* bl = pl + (size_t)ct * 8192;
        f32x16 a0, a1, a2;
        #pragma unroll
        for (int i = 0; i < 16; i++) { a0[i] = 0.f; a1[i] = 0.f; a2[i] = 0.f; }
        #pragma unroll
        for (int s = 0; s < 8; s++) {        // const offsets: 0..7168
            f16x8 eh = *(const f16x8*)(bh + s * 1024);
            f16x8 el = *(const f16x8*)(bl + s * 1024);
            a0 = __builtin_amdgcn_mfma_f32_32x32x16_f16(eh, xh[s], a0, 0, 0, 0);
            a1 = __builtin_amdgcn_mfma_f32_32x32x16_f16(el, xh[s], a1, 0, 0, 0);
            a2 = __builtin_amdgcn_mfma_f32_32x32x16_f16(eh, xl[s], a2, 0, 0, 0);
        }
        // enc-fill stores (younger than this iter's loads; nothing ever waits
        // on them — no barriers in this kernel; they retire to kernel end)
        #pragma unroll
        for (int i = 0; i < 4; i++)
            dstf[ct * 1024 + i * 256] = z4;

        // D: code = (r&3) + 8*(r>>2) + 4*half (ascending per lane), col = row.
        int cb = k0g + ct * 32 + 4 * half;
        #pragma unroll
        for (int gq = 0; gq < 4; gq++) {
            float4 h4 = *(const float4*)(hn + k0g + ct * 32 + gq * 8 + half * 4);
            #pragma unroll
            for (int j = 0; j < 4; j++) {
                int r = gq * 4 + j;
                float hv = (j == 0) ? h4.x : (j == 1) ? h4.y : (j == 2) ? h4.z : h4.w;
                float sc = a0[r] + (a1[r] + a2[r]) * (1.0f / 2048.0f) - hv;
                int cv = cb + gq * 8 + j;
                if (sc > best) { best = sc; bidx = cv; }  // > keeps first (min idx)
            }
        }
    }

    // merge lane <-> lane^32 (same row, disjoint code halves), then atomic.
    {
        float qs = __shfl_xor(best, 32, 64);
        int qi = __shfl_xor(bidx, 32, 64);
        if (qs > best || (qs == best && qi < bidx)) { best = qs; bidx = qi; }
        if (half == 0) {
            unsigned ub = __float_as_uint(best);
            ub = ((int)ub < 0) ? ~ub : (ub | 0x80000000u);   // sortable map
            unsigned long long p = ((unsigned long long)ub << 32) |
                                   (unsigned long long)(0xFFFFFFFFu - (unsigned)bidx);
            atomicMax(&bestg[row], p);                        // tie -> min idx
        }
    }
}

// K3: decode packed best, write one-hot 1.0, gather e[bi] -> NCHW output.
// 128 blocks: 4-way channel split per n.
__global__ __launch_bounds__(256) void k3_final(const char* __restrict__ wsb,
                                                const float* __restrict__ wgt,
                                                float* __restrict__ out) {
    int bid = blockIdx.x;
    int n = (bid & 31) * 256 + threadIdx.x;   // 0..8191
    int q = bid >> 5;                          // channel quarter 0..3
    unsigned long long p = ((const unsigned long long*)(wsb + BEST_OFF))[n];
    int bi = (int)(0xFFFFFFFFu - (unsigned)(p & 0xFFFFFFFFull));

    if (q == 0)
        out[(size_t)OUT_ENC + (size_t)n * 8192 + bi] = 1.0f;

    // out0[((bq*128 + c)*32 + h)*32 + w], n = bq*1024 + h*32 + w
    int bq = n >> 10, hw = n & 1023;
    float* o = out + (size_t)bq * 131072 + hw + (size_t)q * 32 * 1024;
    const float4* wrow = (const float4*)(wgt + (size_t)bi * 128) + q * 8;
    #pragma unroll
    for (int c4 = 0; c4 < 8; c4++) {
        float4 v = wrow[c4];
        o[(c4 * 4 + 0) * 1024] = v.x;
        o[(c4 * 4 + 1) * 1024] = v.y;
        o[(c4 * 4 + 2) * 1024] = v.z;
        o[(c4 * 4 + 3) * 1024] = v.w;
    }
}

extern "C" void kernel_launch(void* const* d_in, const int* in_sizes, int n_in,
                              void* d_out, int out_size, void* d_ws, size_t ws_size,
                              hipStream_t stream) {
    const float* x = (const float*)d_in[0];   // [8,32,32,128] -> [8192][128]
    const float* e = (const float*)d_in[1];   // [8192][128]
    float* out = (float*)d_out;
    char* ws = (char*)d_ws;

    k1_convert<<<2048, 256, 0, stream>>>(x, e, ws);
    k2_mfma<<<512, 256, 0, stream>>>(ws, out);
    k3_final<<<128, 256, 0, stream>>>(ws, e, out);
}